// Round 3
// baseline (73.873 us; speedup 1.0000x reference)
//
#include <hip/hip_runtime.h>
#include <hip/hip_bf16.h>

// SoftPointRenderer: B=4, K=8, N=256 points -> (B,1,96,96) image.
// img[b,h,w] = sum_p ey[p,h]*ex[p,w]; out = 1-exp(-img).
//
// Phase 1: 512 blocks (4 batches x 128 chunks of 16 pts); each block writes a
//          full 96x96 fp32 partial image to d_ws (float4 stores, no atomics).
//          Small chunks -> 2 blocks/CU co-resident, latency hidden by TLP.
// Phase 2: 36 blocks reduce 128 partials/pixel (4 independent accumulators)
//          and apply 1-exp(-x).

#define HDIM 96
#define WDIM 96
#define PIX   (HDIM * WDIM)        // 9216
#define PTS_PER_BATCH 2048         // K*N
#define P_CHUNK 16                 // points per block
#define CHUNKS  128                // 2048 / 16
#define BATCHES 4
#define NPART   (BATCHES * CHUNKS) // 512 partial images

__global__ __launch_bounds__(256)
void splat_partial_kernel(const float* __restrict__ pts, float* __restrict__ ws) {
    __shared__ float sex[P_CHUNK][WDIM];   // 6 KB
    __shared__ float sey[P_CHUNK][HDIM];   // 6 KB
    __shared__ float su[P_CHUNK], sv[P_CHUNK], sval[P_CHUNK];

    const int b = blockIdx.x >> 7;           // / CHUNKS
    const int c = blockIdx.x & (CHUNKS - 1);
    const int t = threadIdx.x;

    // --- stage 1: project 16 points ---
    if (t < P_CHUNK) {
        const int p = (b * PTS_PER_BATCH + c * P_CHUNK + t) * 3;
        const float x = pts[p + 0];
        const float y = pts[p + 1];
        float z = fmaxf(pts[p + 2], 0.001f);
        const float val = (z > 0.2f && z < 10.0f) ? 1.0f : 0.0f;
        const float inv = __frcp_rn(z);
        su[t] = 60.0f * x * inv + 47.5f;     // cx = (96-1)/2
        sv[t] = 60.0f * y * inv + 47.5f;
        sval[t] = val;
    }
    __syncthreads();

    // --- stage 2: separable exp tables: 16*96 entries each, 6 per thread ---
    const float kcoef = -1.0f / (2.0f * 1.5f * 1.5f);
#pragma unroll
    for (int i = t; i < P_CHUNK * 96; i += 256) {
        const int p = i / 96;
        const int cidx = i - p * 96;
        const float fc = (float)cidx;
        const float du = fc - su[p];
        const float dv = fc - sv[p];
        sex[p][cidx] = __expf(kcoef * du * du);
        sey[p][cidx] = __expf(kcoef * dv * dv) * sval[p];
    }
    __syncthreads();

    // --- stage 3: 12-wide x 3-tall tile per thread; 16-pt loop fully unrolled ---
    const int tw = t & 7;        // 8 col-tiles of 12 (16B-aligned -> ds_read_b128)
    const int th = t >> 3;       // 32 row-groups of 3
    const int w0 = tw * 12;
    const int h0 = th * 3;

    float acc[3][12];
#pragma unroll
    for (int i = 0; i < 3; ++i)
#pragma unroll
        for (int j = 0; j < 12; ++j) acc[i][j] = 0.0f;

#pragma unroll
    for (int p = 0; p < P_CHUNK; ++p) {
        const float4* exv = (const float4*)&sex[p][w0];
        const float4 e0 = exv[0], e1 = exv[1], e2 = exv[2];
        const float ex[12] = { e0.x, e0.y, e0.z, e0.w, e1.x, e1.y, e1.z, e1.w,
                               e2.x, e2.y, e2.z, e2.w };
        float ey[3];
#pragma unroll
        for (int i = 0; i < 3; ++i) ey[i] = sey[p][h0 + i];
#pragma unroll
        for (int i = 0; i < 3; ++i)
#pragma unroll
            for (int j = 0; j < 12; ++j) acc[i][j] = fmaf(ey[i], ex[j], acc[i][j]);
    }

    // --- stage 4: float4 stores of the partial image ---
    float* base = ws + (size_t)blockIdx.x * PIX;
#pragma unroll
    for (int i = 0; i < 3; ++i) {
        float4* dst = (float4*)&base[(h0 + i) * WDIM + w0];
#pragma unroll
        for (int q = 0; q < 3; ++q)
            dst[q] = make_float4(acc[i][4*q+0], acc[i][4*q+1], acc[i][4*q+2], acc[i][4*q+3]);
    }
}

__global__ __launch_bounds__(256)
void reduce_finish_kernel(const float* __restrict__ ws, float* __restrict__ out) {
    // one float4 (4 pixels) per thread; 4*9216/4 = 9216 threads = 36 blocks
    const int g = blockIdx.x * 256 + threadIdx.x;      // float4 index
    const int b = g / (PIX / 4);
    const int p4 = g - b * (PIX / 4);

    const float4* w4 = (const float4*)ws;
    const size_t stride = PIX / 4;
    const float4* src = w4 + (size_t)b * CHUNKS * stride + p4;

    float4 s0 = make_float4(0.f,0.f,0.f,0.f), s1 = s0, s2 = s0, s3 = s0;
#pragma unroll 8
    for (int c = 0; c < CHUNKS; c += 4) {
        const float4 v0 = src[(size_t)(c + 0) * stride];
        const float4 v1 = src[(size_t)(c + 1) * stride];
        const float4 v2 = src[(size_t)(c + 2) * stride];
        const float4 v3 = src[(size_t)(c + 3) * stride];
        s0.x += v0.x; s0.y += v0.y; s0.z += v0.z; s0.w += v0.w;
        s1.x += v1.x; s1.y += v1.y; s1.z += v1.z; s1.w += v1.w;
        s2.x += v2.x; s2.y += v2.y; s2.z += v2.z; s2.w += v2.w;
        s3.x += v3.x; s3.y += v3.y; s3.z += v3.z; s3.w += v3.w;
    }
    float4 s;
    s.x = (s0.x + s1.x) + (s2.x + s3.x);
    s.y = (s0.y + s1.y) + (s2.y + s3.y);
    s.z = (s0.z + s1.z) + (s2.z + s3.z);
    s.w = (s0.w + s1.w) + (s2.w + s3.w);

    float4 r;
    r.x = 1.0f - __expf(-s.x);
    r.y = 1.0f - __expf(-s.y);
    r.z = 1.0f - __expf(-s.z);
    r.w = 1.0f - __expf(-s.w);
    ((float4*)out)[g] = r;
}

extern "C" void kernel_launch(void* const* d_in, const int* in_sizes, int n_in,
                              void* d_out, int out_size, void* d_ws, size_t ws_size,
                              hipStream_t stream) {
    const float* pts = (const float*)d_in[0];
    float* ws  = (float*)d_ws;
    float* out = (float*)d_out;

    splat_partial_kernel<<<NPART, 256, 0, stream>>>(pts, ws);
    reduce_finish_kernel<<<(BATCHES * PIX / 4) / 256, 256, 0, stream>>>(ws, out);
}

// Round 4
// 62.883 us; speedup vs baseline: 1.1748x; 1.1748x over previous
//
#include <hip/hip_runtime.h>
#include <hip/hip_bf16.h>

// SoftPointRenderer: B=4, K=8, N=256 points -> (B,1,96,96) image.
// img[b,h,w] = sum_p ey[p,h]*ex[p,w]; out = 1-exp(-img).
//
// Phase 1: 128 blocks (4 batches x 32 chunks of 64 pts); each block writes a
//          full 96x96 fp32 partial image to d_ws (float4 stores, no atomics).
// Phase 2: 144 blocks, one pixel per thread, reduce 32 partials (fully
//          unrolled, 4 independent accumulators) and apply 1-exp(-x).
// ws round-trip kept minimal (4.7 MB each way) — R3 showed partial-count
// inflation costs ~2.5 µs per 10 MB of extra traffic.

#define HDIM 96
#define WDIM 96
#define PIX   (HDIM * WDIM)        // 9216
#define PTS_PER_BATCH 2048         // K*N
#define P_CHUNK 64                 // points per block
#define CHUNKS  32                 // 2048 / 64
#define BATCHES 4
#define NPART   (BATCHES * CHUNKS) // 128 partial images

__global__ __launch_bounds__(256)
void splat_partial_kernel(const float* __restrict__ pts, float* __restrict__ ws) {
    __shared__ float sex[P_CHUNK][WDIM];   // 24 KB
    __shared__ float sey[P_CHUNK][HDIM];   // 24 KB
    __shared__ float su[P_CHUNK], sv[P_CHUNK];

    const int b = blockIdx.x >> 5;           // / CHUNKS
    const int c = blockIdx.x & (CHUNKS - 1);
    const int t = threadIdx.x;

    // --- stage 1: project 64 points (threads 0..63) ---
    if (t < P_CHUNK) {
        const int p = (b * PTS_PER_BATCH + c * P_CHUNK + t) * 3;
        const float x = pts[p + 0];
        const float y = pts[p + 1];
        float z = fmaxf(pts[p + 2], 0.001f);
        const bool valid = (z > 0.2f && z < 10.0f);
        const float inv = __frcp_rn(z);
        su[t] = 60.0f * x * inv + 47.5f;               // cx = (96-1)/2
        // invalid -> v pushed far off-screen so ey == 0 for every row
        sv[t] = valid ? (60.0f * y * inv + 47.5f) : 1.0e9f;
    }
    __syncthreads();

    // --- stage 2: separable exp tables (64*96 each; 24 iters/thread, 2 exps) ---
    const float kcoef = -1.0f / (2.0f * 1.5f * 1.5f);  // -0.5/sigma^2
    for (int i = t; i < P_CHUNK * 96; i += 256) {
        const int p = i / 96;
        const int cidx = i - p * 96;
        const float fc = (float)cidx;
        const float du = fc - su[p];
        const float dv = fc - sv[p];
        sex[p][cidx] = __expf(kcoef * du * du);
        sey[p][cidx] = __expf(kcoef * dv * dv);
    }
    __syncthreads();

    // --- stage 3: 12-wide x 3-tall tile per thread ---
    const int tw = t & 7;        // 8 col-tiles of 12 (16B-aligned -> ds_read_b128)
    const int th = t >> 3;       // 32 row-groups of 3
    const int w0 = tw * 12;
    const int h0 = th * 3;

    float acc[3][12];
#pragma unroll
    for (int i = 0; i < 3; ++i)
#pragma unroll
        for (int j = 0; j < 12; ++j) acc[i][j] = 0.0f;

#pragma unroll
    for (int p = 0; p < P_CHUNK; ++p) {
        const float4* exv = (const float4*)&sex[p][w0];
        const float4 e0 = exv[0], e1 = exv[1], e2 = exv[2];
        const float ex[12] = { e0.x, e0.y, e0.z, e0.w, e1.x, e1.y, e1.z, e1.w,
                               e2.x, e2.y, e2.z, e2.w };
        float ey[3];
#pragma unroll
        for (int i = 0; i < 3; ++i) ey[i] = sey[p][h0 + i];
#pragma unroll
        for (int i = 0; i < 3; ++i)
#pragma unroll
            for (int j = 0; j < 12; ++j) acc[i][j] = fmaf(ey[i], ex[j], acc[i][j]);
    }

    // --- stage 4: float4 stores of the partial image ---
    float* base = ws + (size_t)blockIdx.x * PIX;
#pragma unroll
    for (int i = 0; i < 3; ++i) {
        float4* dst = (float4*)&base[(h0 + i) * WDIM + w0];
#pragma unroll
        for (int q = 0; q < 3; ++q)
            dst[q] = make_float4(acc[i][4*q+0], acc[i][4*q+1], acc[i][4*q+2], acc[i][4*q+3]);
    }
}

__global__ __launch_bounds__(256)
void reduce_finish_kernel(const float* __restrict__ ws, float* __restrict__ out) {
    // one pixel per thread: 36864 threads = 144 blocks (4x parallelism vs float4)
    const int g = blockIdx.x * 256 + threadIdx.x;      // global pixel id
    const int b = g / PIX;
    const int i = g - b * PIX;

    const float* src = ws + (size_t)b * CHUNKS * PIX + i;

    float s0 = 0.f, s1 = 0.f, s2 = 0.f, s3 = 0.f;
#pragma unroll
    for (int c = 0; c < CHUNKS; c += 4) {
        s0 += src[(size_t)(c + 0) * PIX];
        s1 += src[(size_t)(c + 1) * PIX];
        s2 += src[(size_t)(c + 2) * PIX];
        s3 += src[(size_t)(c + 3) * PIX];
    }
    const float s = (s0 + s1) + (s2 + s3);
    out[g] = 1.0f - __expf(-s);
}

extern "C" void kernel_launch(void* const* d_in, const int* in_sizes, int n_in,
                              void* d_out, int out_size, void* d_ws, size_t ws_size,
                              hipStream_t stream) {
    const float* pts = (const float*)d_in[0];
    float* ws  = (float*)d_ws;
    float* out = (float*)d_out;

    splat_partial_kernel<<<NPART, 256, 0, stream>>>(pts, ws);
    reduce_finish_kernel<<<(BATCHES * PIX) / 256, 256, 0, stream>>>(ws, out);
}

// Round 5
// 61.288 us; speedup vs baseline: 1.2053x; 1.0260x over previous
//
#include <hip/hip_runtime.h>
#include <hip/hip_fp16.h>

// SoftPointRenderer: B=4, K=8, N=256 points -> (B,1,96,96) image.
// img[b,h,w] = sum_p ey[p,h]*ex[p,w]; out = 1-exp(-img).
//
// Phase 1: 256 blocks = 4 batches x 32 chunks (64 pts) x 2 row-halves.
//          Each block computes a 48-row half of a 96x96 partial image and
//          stores it as fp16 (ws round-trip halved vs fp32; err bound
//          <= 4.9e-4/e ~ 1.8e-4 on the final output). All 256 CUs busy.
// Phase 2: 72 blocks, 2 px/thread via __half2, reduce 32 partials with 4
//          independent accumulators, apply 1-exp(-x).
// Calibration (R3 vs R4): ws traffic costs ~3.5 us per 10 MB round-trip.

#define HDIM 96
#define WDIM 96
#define PIX   (HDIM * WDIM)        // 9216
#define HHALF 48                   // rows per phase-1 block
#define PTS_PER_BATCH 2048         // K*N
#define P_CHUNK 64                 // points per partial
#define CHUNKS  32                 // 2048 / 64
#define BATCHES 4
#define NPART   (BATCHES * CHUNKS) // 128 partial images (each written by 2 blocks)

__global__ __launch_bounds__(256)
void splat_partial_kernel(const float* __restrict__ pts, __half* __restrict__ ws) {
    __shared__ float sex[P_CHUNK][WDIM];    // 24 KB
    __shared__ float sey[P_CHUNK][HHALF];   // 12 KB
    __shared__ float su[P_CHUNK], sv[P_CHUNK];

    const int b    = blockIdx.x >> 6;          // / (CHUNKS*2)
    const int c    = (blockIdx.x >> 1) & (CHUNKS - 1);
    const int half = blockIdx.x & 1;           // row-half: rows [half*48, half*48+48)
    const int t = threadIdx.x;

    // --- stage 1: project 64 points (threads 0..63) ---
    if (t < P_CHUNK) {
        const int p = (b * PTS_PER_BATCH + c * P_CHUNK + t) * 3;
        const float x = pts[p + 0];
        const float y = pts[p + 1];
        float z = fmaxf(pts[p + 2], 0.001f);
        const bool valid = (z > 0.2f && z < 10.0f);
        const float inv = __frcp_rn(z);
        su[t] = 60.0f * x * inv + 47.5f;               // cx = (96-1)/2
        // invalid -> v pushed far off-screen so ey == 0 for every row
        sv[t] = valid ? (60.0f * y * inv + 47.5f) : 1.0e9f;
    }
    __syncthreads();

    // --- stage 2: separable exp tables ---
    const float kcoef = -1.0f / (2.0f * 1.5f * 1.5f);  // -0.5/sigma^2
    const float rowbase = (float)(half * HHALF);
    for (int i = t; i < P_CHUNK * WDIM; i += 256) {    // 24 iters
        const int p = i / WDIM;
        const int cidx = i - p * WDIM;
        const float du = (float)cidx - su[p];
        sex[p][cidx] = __expf(kcoef * du * du);
    }
    for (int i = t; i < P_CHUNK * HHALF; i += 256) {   // 12 iters
        const int p = i / HHALF;
        const int r = i - p * HHALF;
        const float dv = rowbase + (float)r - sv[p];
        sey[p][r] = __expf(kcoef * dv * dv);
    }
    __syncthreads();

    // --- stage 3: 6-wide x 3-tall tile per thread (16 tw x 16 th = 256) ---
    const int tw = t & 15;
    const int th = t >> 4;
    const int w0 = tw * 6;       // even -> 8-B aligned float2 LDS reads
    const int r0 = th * 3;       // local row within this half

    float acc[3][6];
#pragma unroll
    for (int i = 0; i < 3; ++i)
#pragma unroll
        for (int j = 0; j < 6; ++j) acc[i][j] = 0.0f;

#pragma unroll
    for (int p = 0; p < P_CHUNK; ++p) {
        const float2 e0 = *(const float2*)&sex[p][w0 + 0];
        const float2 e1 = *(const float2*)&sex[p][w0 + 2];
        const float2 e2 = *(const float2*)&sex[p][w0 + 4];
        const float ex[6] = { e0.x, e0.y, e1.x, e1.y, e2.x, e2.y };
        float ey[3];
#pragma unroll
        for (int i = 0; i < 3; ++i) ey[i] = sey[p][r0 + i];
#pragma unroll
        for (int i = 0; i < 3; ++i)
#pragma unroll
            for (int j = 0; j < 6; ++j) acc[i][j] = fmaf(ey[i], ex[j], acc[i][j]);
    }

    // --- stage 4: fp16 stores (3 half2 per row x 3 rows) ---
    const int part = b * CHUNKS + c;
    __half* base = ws + (size_t)part * PIX;
#pragma unroll
    for (int i = 0; i < 3; ++i) {
        __half2* dst = (__half2*)&base[(half * HHALF + r0 + i) * WDIM + w0];
#pragma unroll
        for (int q = 0; q < 3; ++q)
            dst[q] = __floats2half2_rn(acc[i][2*q + 0], acc[i][2*q + 1]);
    }
}

__global__ __launch_bounds__(256)
void reduce_finish_kernel(const __half2* __restrict__ ws, float2* __restrict__ out) {
    // 2 pixels (one half2) per thread: 18432 threads = 72 blocks
    const int g = blockIdx.x * 256 + threadIdx.x;      // half2 index
    const int b = g / (PIX / 2);
    const int i = g - b * (PIX / 2);

    const __half2* src = ws + (size_t)b * CHUNKS * (PIX / 2) + i;

    float2 s0 = make_float2(0.f, 0.f), s1 = s0, s2 = s0, s3 = s0;
#pragma unroll
    for (int c = 0; c < CHUNKS; c += 4) {
        const float2 v0 = __half22float2(src[(size_t)(c + 0) * (PIX / 2)]);
        const float2 v1 = __half22float2(src[(size_t)(c + 1) * (PIX / 2)]);
        const float2 v2 = __half22float2(src[(size_t)(c + 2) * (PIX / 2)]);
        const float2 v3 = __half22float2(src[(size_t)(c + 3) * (PIX / 2)]);
        s0.x += v0.x; s0.y += v0.y;
        s1.x += v1.x; s1.y += v1.y;
        s2.x += v2.x; s2.y += v2.y;
        s3.x += v3.x; s3.y += v3.y;
    }
    const float sx = (s0.x + s1.x) + (s2.x + s3.x);
    const float sy = (s0.y + s1.y) + (s2.y + s3.y);

    out[g] = make_float2(1.0f - __expf(-sx), 1.0f - __expf(-sy));
}

extern "C" void kernel_launch(void* const* d_in, const int* in_sizes, int n_in,
                              void* d_out, int out_size, void* d_ws, size_t ws_size,
                              hipStream_t stream) {
    const float* pts = (const float*)d_in[0];
    __half* ws = (__half*)d_ws;
    float2* out = (float2*)d_out;

    splat_partial_kernel<<<NPART * 2, 256, 0, stream>>>(pts, ws);
    reduce_finish_kernel<<<(BATCHES * PIX / 2) / 256, 256, 0, stream>>>(
        (const __half2*)ws, out);
}